// Round 1
// baseline (9.742 us; speedup 1.0000x reference)
//
#include <hip/hip_runtime.h>

// out[row, :] = weight[ids[row], :]
// rows = B*L = 8192, D = 128 floats = 32 float4 per row.
// 32 lanes cooperate on one row; each lane moves one float4.
__global__ void soft_embedding_gather(const int* __restrict__ ids,
                                      const float4* __restrict__ w4,
                                      float4* __restrict__ out4,
                                      int n_rows) {
    const int gid = blockIdx.x * blockDim.x + threadIdx.x;
    const int row = gid >> 5;       // 32 threads per row
    const int c   = gid & 31;       // float4 index within row (D/4 = 32)
    if (row >= n_rows) return;
    const int id = ids[row];
    out4[(size_t)row * 32 + c] = w4[(size_t)id * 32 + c];
}

extern "C" void kernel_launch(void* const* d_in, const int* in_sizes, int n_in,
                              void* d_out, int out_size, void* d_ws, size_t ws_size,
                              hipStream_t stream) {
    const int*   ids = (const int*)d_in[0];     // [B*L] = 8192
    const float* w   = (const float*)d_in[1];   // [32000, 128]
    float*       out = (float*)d_out;           // [B*L, 128]

    const int n_rows = in_sizes[0];             // 8192
    const int total  = n_rows * 32;             // threads: 32 per row
    const int block  = 256;
    const int grid   = (total + block - 1) / block;

    soft_embedding_gather<<<grid, block, 0, stream>>>(
        ids, (const float4*)w, (float4*)out, n_rows);
}